// Round 2
// baseline (1381.456 us; speedup 1.0000x reference)
//
#include <hip/hip_runtime.h>
#include <hip/hip_bf16.h>

#define N_CH_IN 768
#define N_CH_HID 256
#define N_CH_OUT 2

// ---------------------------------------------------------------- init
__global__ __launch_bounds__(256) void k_init(float* __restrict__ deg,
                                              int* __restrict__ counts, int n) {
    int i = blockIdx.x * 256 + threadIdx.x;
    if (i < n) { deg[i] = 1.0f; counts[i] = 0; }
}

// ------------------------------------------------------- degree + hist
__global__ __launch_bounds__(256) void k_deg_count(const int* __restrict__ dst,
                                                   const float* __restrict__ w,
                                                   float* __restrict__ deg,
                                                   int* __restrict__ counts, int e) {
    int i = blockIdx.x * 256 + threadIdx.x;
    if (i < e) {
        int d = dst[i];
        atomicAdd(&deg[d], w[i]);
        atomicAdd(&counts[d], 1);
    }
}

__global__ __launch_bounds__(256) void k_dinv(const float* __restrict__ deg,
                                              float* __restrict__ dinv, int n) {
    int i = blockIdx.x * 256 + threadIdx.x;
    if (i < n) {
        float d = deg[i];
        dinv[i] = (d > 0.0f) ? rsqrtf(d) : 0.0f;
    }
}

// ---------------------------------------------------------------- scan
__global__ __launch_bounds__(1024) void k_scan_block(const int* __restrict__ counts,
                                                     int* __restrict__ row_start,
                                                     int* __restrict__ block_sums, int n) {
    __shared__ int sm[1024];
    int t = threadIdx.x;
    int g = blockIdx.x * 1024 + t;
    int v = (g < n) ? counts[g] : 0;
    int x = v;
    sm[t] = v;
    __syncthreads();
    for (int off = 1; off < 1024; off <<= 1) {
        int y = (t >= off) ? sm[t - off] : 0;
        __syncthreads();
        x += y;
        sm[t] = x;
        __syncthreads();
    }
    if (g < n) row_start[g] = x - v;           // exclusive, pre-offset
    if (t == 1023) block_sums[blockIdx.x] = x; // block total
}

__global__ void k_scan_tops(const int* __restrict__ block_sums,
                            int* __restrict__ block_offs, int nb) {
    if (threadIdx.x == 0 && blockIdx.x == 0) {
        int off = 0;
        for (int b = 0; b < nb; b++) { block_offs[b] = off; off += block_sums[b]; }
    }
}

__global__ __launch_bounds__(1024) void k_scan_add(int* __restrict__ row_start,
                                                   int* __restrict__ cursor,
                                                   const int* __restrict__ block_offs, int n) {
    int g = blockIdx.x * 1024 + threadIdx.x;
    if (g < n) {
        int v = row_start[g] + block_offs[blockIdx.x];
        row_start[g] = v;
        cursor[g] = v;
    }
}

// ------------------------------------------------------------- scatter
__global__ __launch_bounds__(256) void k_scatter(const int* __restrict__ src,
                                                 const int* __restrict__ dst,
                                                 const float* __restrict__ w,
                                                 const float* __restrict__ dinv,
                                                 int* __restrict__ cursor,
                                                 int* __restrict__ col,
                                                 float* __restrict__ val, int e) {
    int i = blockIdx.x * 256 + threadIdx.x;
    if (i < e) {
        int s = src[i];
        int d = dst[i];
        float nv = dinv[s] * w[i] * dinv[d];
        int pos = atomicAdd(&cursor[d], 1);
        col[pos] = s;
        val[pos] = nv;
    }
}

// ---------------------------------------------------------- GEMM1 fp32
// xw[M,256] = X[M,768] @ W[768,256]; BM=BN=64, BK=16, 256 thr, 4x4 microtile
__global__ __launch_bounds__(256) void k_gemm1(const float* __restrict__ X,
                                               const float* __restrict__ W,
                                               float* __restrict__ XW, int M) {
    const int K = N_CH_IN, N = N_CH_HID;
    __shared__ float As[16][68];
    __shared__ float Bs[16][64];
    int bm = blockIdx.x * 64;
    int bn = blockIdx.y * 64;
    int t = threadIdx.x;
    int tx = t & 15, ty = t >> 4;
    int ar = t >> 2;
    int ak = (t & 3) * 4;
    float acc[4][4] = {};
    for (int k0 = 0; k0 < K; k0 += 16) {
        float4 av = make_float4(0.f, 0.f, 0.f, 0.f);
        int grow = bm + ar;
        if (grow < M) av = *(const float4*)(X + (size_t)grow * K + k0 + ak);
        As[ak + 0][ar] = av.x;
        As[ak + 1][ar] = av.y;
        As[ak + 2][ar] = av.z;
        As[ak + 3][ar] = av.w;
#pragma unroll
        for (int i = 0; i < 4; i++) {
            int idx = t + i * 256;
            int kk = idx >> 6, c = idx & 63;
            Bs[kk][c] = W[(size_t)(k0 + kk) * N + bn + c];
        }
        __syncthreads();
#pragma unroll
        for (int kk = 0; kk < 16; kk++) {
            float4 a4 = *(const float4*)&As[kk][ty * 4];
            float4 b4 = *(const float4*)&Bs[kk][tx * 4];
            float a[4] = {a4.x, a4.y, a4.z, a4.w};
            float b[4] = {b4.x, b4.y, b4.z, b4.w};
#pragma unroll
            for (int i = 0; i < 4; i++)
#pragma unroll
                for (int j = 0; j < 4; j++)
                    acc[i][j] = fmaf(a[i], b[j], acc[i][j]);
        }
        __syncthreads();
    }
#pragma unroll
    for (int i = 0; i < 4; i++) {
        int r = bm + ty * 4 + i;
        if (r < M) {
            float4 v = make_float4(acc[i][0], acc[i][1], acc[i][2], acc[i][3]);
            *(float4*)(XW + (size_t)r * N + bn + tx * 4) = v;
        }
    }
}

// ----------------------------------- aggregation layer 1 + GEMM2 fused
// one wave per node; lane owns 4 channels (float4):
//   h_row = relu(sum_j norm_j * xw[col_j] + dinv^2 * xw[node] + b1)
//   hw[node] = h_row @ W2   (in-wave shuffle reduce, 2 outputs)
__global__ __launch_bounds__(256) void k_agg1_gemm2(const float* __restrict__ xw,
                                                    const int* __restrict__ row_start,
                                                    const int* __restrict__ counts,
                                                    const int* __restrict__ col,
                                                    const float* __restrict__ val,
                                                    const float* __restrict__ dinv,
                                                    const float* __restrict__ b1,
                                                    const float* __restrict__ W2,
                                                    float* __restrict__ hw, int n) {
    int wid = threadIdx.x >> 6;
    int lane = threadIdx.x & 63;
    int node = blockIdx.x * 4 + wid;
    if (node >= n) return;
    int start = row_start[node];
    int cnt = counts[node];
    float4 acc = make_float4(0.f, 0.f, 0.f, 0.f);
    for (int j = 0; j < cnt; j++) {
        int s = col[start + j];
        float v = val[start + j];
        float4 r = *(const float4*)(xw + (size_t)s * N_CH_HID + lane * 4);
        acc.x = fmaf(r.x, v, acc.x);
        acc.y = fmaf(r.y, v, acc.y);
        acc.z = fmaf(r.z, v, acc.z);
        acc.w = fmaf(r.w, v, acc.w);
    }
    float dn = dinv[node];
    float sv = dn * dn; // self loop norm
    float4 r = *(const float4*)(xw + (size_t)node * N_CH_HID + lane * 4);
    acc.x = fmaf(r.x, sv, acc.x);
    acc.y = fmaf(r.y, sv, acc.y);
    acc.z = fmaf(r.z, sv, acc.z);
    acc.w = fmaf(r.w, sv, acc.w);
    float4 bb = *(const float4*)(b1 + lane * 4);
    acc.x = fmaxf(acc.x + bb.x, 0.f);
    acc.y = fmaxf(acc.y + bb.y, 0.f);
    acc.z = fmaxf(acc.z + bb.z, 0.f);
    acc.w = fmaxf(acc.w + bb.w, 0.f);
    // fused GEMM2: 2 output channels via wave reduce
    int k = lane * 4;
    float s0 = acc.x * W2[(k + 0) * 2 + 0] + acc.y * W2[(k + 1) * 2 + 0] +
               acc.z * W2[(k + 2) * 2 + 0] + acc.w * W2[(k + 3) * 2 + 0];
    float s1 = acc.x * W2[(k + 0) * 2 + 1] + acc.y * W2[(k + 1) * 2 + 1] +
               acc.z * W2[(k + 2) * 2 + 1] + acc.w * W2[(k + 3) * 2 + 1];
#pragma unroll
    for (int off = 32; off; off >>= 1) {
        s0 += __shfl_xor(s0, off);
        s1 += __shfl_xor(s1, off);
    }
    if (lane == 0) {
        hw[(size_t)node * 2 + 0] = s0;
        hw[(size_t)node * 2 + 1] = s1;
    }
}

// ------------------------------------------------- aggregation layer 2
// one thread per node (only 2 channels; hw is L2-resident, 800KB)
__global__ __launch_bounds__(256) void k_agg2(const float* __restrict__ hw,
                                              const int* __restrict__ row_start,
                                              const int* __restrict__ counts,
                                              const int* __restrict__ col,
                                              const float* __restrict__ val,
                                              const float* __restrict__ dinv,
                                              const float* __restrict__ b2,
                                              float* __restrict__ out, int n) {
    int node = blockIdx.x * 256 + threadIdx.x;
    if (node >= n) return;
    int start = row_start[node];
    int cnt = counts[node];
    float o0 = 0.f, o1 = 0.f;
    for (int j = 0; j < cnt; j++) {
        int s = col[start + j];
        float v = val[start + j];
        o0 = fmaf(hw[(size_t)s * 2 + 0], v, o0);
        o1 = fmaf(hw[(size_t)s * 2 + 1], v, o1);
    }
    float dn = dinv[node];
    float sv = dn * dn;
    o0 = fmaf(hw[(size_t)node * 2 + 0], sv, o0);
    o1 = fmaf(hw[(size_t)node * 2 + 1], sv, o1);
    out[(size_t)node * 2 + 0] = o0 + b2[0];
    out[(size_t)node * 2 + 1] = o1 + b2[1];
}

// ---------------------------------------------------------------------
extern "C" void kernel_launch(void* const* d_in, const int* in_sizes, int n_in,
                              void* d_out, int out_size, void* d_ws, size_t ws_size,
                              hipStream_t stream) {
    const float* x = (const float*)d_in[0];
    const int* ei = (const int*)d_in[1];   // harness passes integer inputs as int32
    const float* ew = (const float*)d_in[2];
    const float* W1 = (const float*)d_in[3];
    const float* b1 = (const float*)d_in[4];
    const float* W2 = (const float*)d_in[5];
    const float* b2 = (const float*)d_in[6];
    float* out = (float*)d_out;

    const int N = in_sizes[0] / N_CH_IN;   // 100000
    const int E = in_sizes[2];             // 1600000
    const int* src = ei;
    const int* dst = ei + E;

    // workspace carve (256B aligned); total ~118 MB
    char* p = (char*)d_ws;
    auto alloc = [&](size_t bytes) {
        void* r = (void*)p;
        p += (bytes + 255) & ~(size_t)255;
        return r;
    };
    float* xw        = (float*)alloc((size_t)N * N_CH_HID * 4);
    float* hw        = (float*)alloc((size_t)N * 2 * 4);
    float* deg       = (float*)alloc((size_t)N * 4);
    float* dinv      = (float*)alloc((size_t)N * 4);
    int*   counts    = (int*)alloc((size_t)N * 4);
    int*   row_start = (int*)alloc((size_t)N * 4);
    int*   cursor    = (int*)alloc((size_t)N * 4);
    int*   col       = (int*)alloc((size_t)E * 4);
    float* val       = (float*)alloc((size_t)E * 4);
    int*   bsums     = (int*)alloc(1024);
    int*   boffs     = (int*)alloc(1024);

    const int nblkN = (N + 255) / 256;
    const int nblkE = (E + 255) / 256;
    const int nbScan = (N + 1023) / 1024;

    k_init<<<nblkN, 256, 0, stream>>>(deg, counts, N);
    k_deg_count<<<nblkE, 256, 0, stream>>>(dst, ew, deg, counts, E);
    k_dinv<<<nblkN, 256, 0, stream>>>(deg, dinv, N);
    k_scan_block<<<nbScan, 1024, 0, stream>>>(counts, row_start, bsums, N);
    k_scan_tops<<<1, 64, 0, stream>>>(bsums, boffs, nbScan);
    k_scan_add<<<nbScan, 1024, 0, stream>>>(row_start, cursor, boffs, N);
    k_scatter<<<nblkE, 256, 0, stream>>>(src, dst, ew, dinv, cursor, col, val, E);

    dim3 g1((N + 63) / 64, N_CH_HID / 64);
    k_gemm1<<<g1, 256, 0, stream>>>(x, W1, xw, N);

    k_agg1_gemm2<<<(N + 3) / 4, 256, 0, stream>>>(xw, row_start, counts, col, val,
                                                  dinv, b1, W2, hw, N);
    k_agg2<<<nblkN, 256, 0, stream>>>(hw, row_start, counts, col, val, dinv, b2, out, N);
}